// Round 14
// baseline (334.028 us; speedup 1.0000x reference)
//
#include <hip/hip_runtime.h>
#include <hip/hip_bf16.h>
#include <math.h>

#define HH 64            // hidden channels
#define EPS 1e-5f
#define STAGE_CAP 12288  // per-bucket LDS staging capacity (3x avg bucket size)
#define NBLK_SCAT 192    // partition blocks (must match between hist and scatter)
#define PER_LANE 3       // ceil(NBLK_SCAT / 64)

// ---------------------------------------------------------------- utilities
__device__ __forceinline__ int lower_bound_i(const int* a, int n, int key) {
    int lo = 0, hi = n;
    while (lo < hi) { int mid = (lo + hi) >> 1; if (a[mid] < key) lo = mid + 1; else hi = mid; }
    return lo;
}

__device__ __forceinline__ unsigned short f2bf(float f) {
    unsigned int u = __float_as_uint(f);
    unsigned int r = (u + 0x7FFFu + ((u >> 16) & 1u)) >> 16;   // RNE
    return (unsigned short)r;
}
__device__ __forceinline__ float bf2f(unsigned short b) {
    return __uint_as_float(((unsigned int)b) << 16);
}
__device__ __forceinline__ float bflo(unsigned int u) { return __uint_as_float(u << 16); }
__device__ __forceinline__ float bfhi(unsigned int u) { return __uint_as_float(u & 0xFFFF0000u); }

// ---------------------------------------------------------------- init (gsum only)
__global__ void init_kernel(float* gsum, int NG) {
    int t = blockIdx.x * blockDim.x + threadIdx.x;
    if (t < NG) gsum[t] = 0.f;
}

// pass A1: per-block histogram over buckets (LDS only, no global atomics)
__global__ __launch_bounds__(256) void hist_kernel(const int* __restrict__ dst,
        int* __restrict__ blockhist, int E, int chunk) {
    __shared__ int hist[256];
    int tid = threadIdx.x, blk = blockIdx.x;
    hist[tid] = 0;
    __syncthreads();
    int s = blk * chunk, e = s + chunk; if (e > E) e = E;
    for (int i = s + tid; i < e; i += 256) atomicAdd(&hist[dst[i] >> 8], 1);
    __syncthreads();
    blockhist[blk * 256 + tid] = hist[tid];
}

// pass A1b: single block; column-sum blockhist -> bucket totals -> exclusive scan
__global__ __launch_bounds__(256) void bucketscan_kernel(const int* __restrict__ blockhist,
        int* __restrict__ bucketbase, int NB, int E) {
    __shared__ int wsum2[4];
    int tid = threadIdx.x, lane = tid & 63, wid = tid >> 6;
    int s = 0;
    if (tid < NB) {
        for (int i = 0; i < NBLK_SCAT; ++i) s += blockhist[i * 256 + tid];
    }
    int incl = s;
    #pragma unroll
    for (int off = 1; off < 64; off <<= 1) {
        int n = __shfl_up(incl, off);
        if (lane >= off) incl += n;
    }
    if (lane == 63) wsum2[wid] = incl;
    __syncthreads();
    int wbase = 0;
    #pragma unroll
    for (int k = 0; k < 4; ++k) if (k < wid) wbase += wsum2[k];
    if (tid < NB) bucketbase[tid] = wbase + incl - s;
    if (tid == 0) bucketbase[NB] = E;
}

// pass A2: per-bucket column scan of blockhist -> per-block write cursors
__global__ __launch_bounds__(64) void offsets_kernel(const int* __restrict__ bucketbase,
        int* __restrict__ blockhist, int NB) {
    int b = blockIdx.x;
    int lane = threadIdx.x;
    int v[PER_LANE];
    int base = lane * PER_LANE;
    int s = 0;
    #pragma unroll
    for (int k = 0; k < PER_LANE; ++k) {
        int i = base + k;
        v[k] = (i < NBLK_SCAT) ? blockhist[i * 256 + b] : 0;
        s += v[k];
    }
    int incl = s;
    #pragma unroll
    for (int off = 1; off < 64; off <<= 1) {
        int n = __shfl_up(incl, off);
        if (lane >= off) incl += n;
    }
    int excl = incl - s + bucketbase[b];
    #pragma unroll
    for (int k = 0; k < PER_LANE; ++k) {
        int i = base + k;
        if (i < NBLK_SCAT) { blockhist[i * 256 + b] = excl; excl += v[k]; }
    }
}

// pass A3: scatter edges to bucket regions using LDS cursors
__global__ __launch_bounds__(256) void scatterA_kernel(const int* __restrict__ src,
        const int* __restrict__ dst, const int* __restrict__ blockhist,
        int* __restrict__ buf, int E, int chunk) {
    __shared__ int lcur[256];
    int tid = threadIdx.x, blk = blockIdx.x;
    lcur[tid] = blockhist[blk * 256 + tid];
    __syncthreads();
    int s = blk * chunk, e = s + chunk; if (e > E) e = E;
    for (int i = s + tid; i < e; i += 256) {
        int d = dst[i];
        int b = d >> 8;
        int p = atomicAdd(&lcur[b], 1);
        buf[p] = ((d & 255) << 24) | src[i];    // pack local-dst | src (src < 2^24)
    }
}

// pass B: per bucket: local degree hist + scan (writes rowstart, dis), permute to csr
__global__ __launch_bounds__(256) void bucket_to_csr_kernel(const int* __restrict__ buf,
        const int* __restrict__ bucketbase, int* __restrict__ rowstart,
        float* __restrict__ dis, int* __restrict__ csr, int N, int E) {
    __shared__ int ldeg[256];
    __shared__ int cur[256];
    __shared__ int wsum2[4];
    __shared__ int stage[STAGE_CAP];
    int b = blockIdx.x;
    int nodeStart = b << 8;
    int nodeEnd = nodeStart + 256; if (nodeEnd > N) nodeEnd = N;
    int nloc = nodeEnd - nodeStart;
    int base = bucketbase[b];
    int nE = bucketbase[b + 1] - base;
    int tid = threadIdx.x;
    int lane = tid & 63, wid = tid >> 6;
    ldeg[tid] = 0;
    __syncthreads();
    for (int i = tid; i < nE; i += 256)
        atomicAdd(&ldeg[((unsigned)buf[base + i]) >> 24], 1);
    __syncthreads();
    int d = ldeg[tid];
    int incl = d;
    #pragma unroll
    for (int off = 1; off < 64; off <<= 1) {
        int n = __shfl_up(incl, off);
        if (lane >= off) incl += n;
    }
    if (lane == 63) wsum2[wid] = incl;
    __syncthreads();
    int wbase = 0;
    #pragma unroll
    for (int k = 0; k < 4; ++k) if (k < wid) wbase += wsum2[k];
    int excl = wbase + incl - d;
    cur[tid] = excl;
    if (tid < nloc) {
        rowstart[nodeStart + tid] = base + excl;
        dis[nodeStart + tid] = rsqrtf((float)d + 1.0f);
    }
    if (b == 0 && tid == 0) rowstart[N] = E;
    __syncthreads();
    if (nE <= STAGE_CAP) {
        for (int i = tid; i < nE; i += 256) {
            int u = buf[base + i];
            int l = ((unsigned)u) >> 24;
            int p = atomicAdd(&cur[l], 1);
            stage[p] = u & 0xFFFFFF;
        }
        __syncthreads();
        for (int i = tid; i < nE; i += 256) csr[base + i] = stage[i];
    } else {
        for (int i = tid; i < nE; i += 256) {
            int u = buf[base + i];
            int l = ((unsigned)u) >> 24;
            int p = atomicAdd(&cur[l], 1);
            csr[base + p] = u & 0xFFFFFF;
        }
    }
}

// ---------------------------------------------------------------- layer 1 GEMM (IN=3) -> bf16 mt
__global__ void mt1_kernel(const float* __restrict__ x, const float* __restrict__ W1,
                           const float* __restrict__ dis, unsigned short* __restrict__ mt, int N) {
    int t = blockIdx.x * blockDim.x + threadIdx.x;
    if (t < N * HH) {
        int v = t >> 6, c = t & 63;
        float m = x[v * 3 + 0] * W1[0 * HH + c]
                + x[v * 3 + 1] * W1[1 * HH + c]
                + x[v * 3 + 2] * W1[2 * HH + c];
        mt[t] = f2bf(m * dis[v]);
    }
}

// ---------------------------------------------------------------- 64x64 GEMM + row scale -> bf16 mt
// One 64-node tile per block. W^T and h tile staged in LDS as packed bf16x2
// (pad 34 -> 2-way bank alias only). Scalar accumulator per thread; uint2 LDS
// reads. No large per-thread arrays -> no spill.
__global__ __launch_bounds__(256) void gemm_scale_kernel(const float* __restrict__ h,
        const float* __restrict__ W, const float* __restrict__ dis,
        unsigned short* __restrict__ mt, int N) {
    __shared__ unsigned int wsp[HH * 34];
    __shared__ unsigned int hs2[64 * 34];
    int tid = threadIdx.x;
    int lane = tid & 63, wid = tid >> 6;
    {
        int c = tid & 63;
        for (int k2 = tid >> 6; k2 < 32; k2 += 4) {
            float a = W[(2 * k2) * HH + c];
            float b = W[(2 * k2 + 1) * HH + c];
            wsp[c * 34 + k2] = (unsigned)f2bf(a) | ((unsigned)f2bf(b) << 16);
        }
    }
    int v0 = blockIdx.x * 64;
    int nv = N - v0; if (nv > 64) nv = 64;
    for (int idx = tid; idx < 64 * 32; idx += 256) {
        int n = idx >> 5, k2 = idx & 31;
        int vsrc = v0 + ((n < nv) ? n : 0);
        float a = h[(size_t)vsrc * HH + 2 * k2];
        float b = h[(size_t)vsrc * HH + 2 * k2 + 1];
        hs2[n * 34 + k2] = (unsigned)f2bf(a) | ((unsigned)f2bf(b) << 16);
    }
    __syncthreads();
    for (int n = wid * 16; n < wid * 16 + 16; ++n) {
        int vg = v0 + n;
        if (n >= nv) break;
        float acc = 0.f;
        #pragma unroll 4
        for (int k2g = 0; k2g < 16; ++k2g) {
            uint2 wv = *(const uint2*)&wsp[lane * 34 + 2 * k2g];
            uint2 hv = *(const uint2*)&hs2[n * 34 + 2 * k2g];
            acc = fmaf(bflo(hv.x), bflo(wv.x), acc);
            acc = fmaf(bfhi(hv.x), bfhi(wv.x), acc);
            acc = fmaf(bflo(hv.y), bflo(wv.y), acc);
            acc = fmaf(bfhi(hv.y), bfhi(wv.y), acc);
        }
        mt[(size_t)vg * HH + lane] = f2bf(acc * dis[vg]);
    }
}

// ---------------------------------------------------------------- gather + bias + BN + ReLU
__global__ __launch_bounds__(256) void gather_bn_kernel(const unsigned short* __restrict__ mt,
        const int* __restrict__ rowstart, const int* __restrict__ csr_src,
        const float* __restrict__ dis, const float* __restrict__ bias,
        const float* __restrict__ gam, const float* __restrict__ beta,
        const float* __restrict__ mu, const float* __restrict__ var,
        float* __restrict__ hout, int N) {
    int lane = threadIdx.x & 63, wid = threadIdx.x >> 6;
    int v = blockIdx.x * 4 + wid;
    if (v >= N) return;
    int start = rowstart[v], end = rowstart[v + 1];
    float acc = bf2f(mt[v * HH + lane]);   // self-loop term (m[v]*dis[v])
    for (int base = start; base < end; base += 64) {
        int idx = (base + lane < end) ? csr_src[base + lane] : 0;
        int cnt = end - base; if (cnt > 64) cnt = 64;
        int j = 0;
        for (; j + 15 < cnt; j += 16) {
            int s0 = __shfl(idx, j),      s1 = __shfl(idx, j + 1);
            int s2 = __shfl(idx, j + 2),  s3 = __shfl(idx, j + 3);
            int s4 = __shfl(idx, j + 4),  s5 = __shfl(idx, j + 5);
            int s6 = __shfl(idx, j + 6),  s7 = __shfl(idx, j + 7);
            int s8 = __shfl(idx, j + 8),  s9 = __shfl(idx, j + 9);
            int sa = __shfl(idx, j + 10), sb = __shfl(idx, j + 11);
            int sc = __shfl(idx, j + 12), sd = __shfl(idx, j + 13);
            int se = __shfl(idx, j + 14), sf = __shfl(idx, j + 15);
            float v0 = bf2f(mt[s0 * HH + lane]);
            float v1 = bf2f(mt[s1 * HH + lane]);
            float v2 = bf2f(mt[s2 * HH + lane]);
            float v3 = bf2f(mt[s3 * HH + lane]);
            float v4 = bf2f(mt[s4 * HH + lane]);
            float v5 = bf2f(mt[s5 * HH + lane]);
            float v6 = bf2f(mt[s6 * HH + lane]);
            float v7 = bf2f(mt[s7 * HH + lane]);
            float v8 = bf2f(mt[s8 * HH + lane]);
            float v9 = bf2f(mt[s9 * HH + lane]);
            float va = bf2f(mt[sa * HH + lane]);
            float vb = bf2f(mt[sb * HH + lane]);
            float vc = bf2f(mt[sc * HH + lane]);
            float vd = bf2f(mt[sd * HH + lane]);
            float ve = bf2f(mt[se * HH + lane]);
            float vf = bf2f(mt[sf * HH + lane]);
            acc += v0; acc += v1; acc += v2; acc += v3;
            acc += v4; acc += v5; acc += v6; acc += v7;
            acc += v8; acc += v9; acc += va; acc += vb;
            acc += vc; acc += vd; acc += ve; acc += vf;
        }
        for (; j + 7 < cnt; j += 8) {
            int s0 = __shfl(idx, j),     s1 = __shfl(idx, j + 1);
            int s2 = __shfl(idx, j + 2), s3 = __shfl(idx, j + 3);
            int s4 = __shfl(idx, j + 4), s5 = __shfl(idx, j + 5);
            int s6 = __shfl(idx, j + 6), s7 = __shfl(idx, j + 7);
            float v0 = bf2f(mt[s0 * HH + lane]);
            float v1 = bf2f(mt[s1 * HH + lane]);
            float v2 = bf2f(mt[s2 * HH + lane]);
            float v3 = bf2f(mt[s3 * HH + lane]);
            float v4 = bf2f(mt[s4 * HH + lane]);
            float v5 = bf2f(mt[s5 * HH + lane]);
            float v6 = bf2f(mt[s6 * HH + lane]);
            float v7 = bf2f(mt[s7 * HH + lane]);
            acc += v0; acc += v1; acc += v2; acc += v3;
            acc += v4; acc += v5; acc += v6; acc += v7;
        }
        for (; j < cnt; ++j) acc += bf2f(mt[__shfl(idx, j) * HH + lane]);
    }
    float val = acc * dis[v] + bias[lane];
    val = (val - mu[lane]) * rsqrtf(var[lane] + EPS) * gam[lane] + beta[lane];
    hout[v * HH + lane] = fmaxf(val, 0.f);
}

// ---------------------------------------------------------------- pool partial sums
__global__ __launch_bounds__(256) void pool_partial_kernel(const float* __restrict__ h,
        const int* __restrict__ batch, float* __restrict__ gsum, int N, int chunk) {
    int lane = threadIdx.x & 63, wid = threadIdx.x >> 6;
    int w = blockIdx.x * 4 + wid;
    int start = w * chunk;
    int end = start + chunk; if (end > N) end = N;
    if (start >= end) return;
    int g = batch[start];
    float acc = 0.f;
    for (int i = start; i < end; ++i) {
        int gi = batch[i];
        if (gi != g) {
            atomicAdd(&gsum[g * HH + lane], acc);
            acc = 0.f; g = gi;
        }
        acc += h[i * HH + lane];
    }
    atomicAdd(&gsum[g * HH + lane], acc);
}

// ---------------------------------------------------------------- MLP heads (+ mean divide)
__global__ __launch_bounds__(64) void heads_kernel(const float* __restrict__ gsum,
        const int* __restrict__ batch, int N,
        const float* __restrict__ thW1, const float* __restrict__ thb1,
        const float* __restrict__ thW2, const float* __restrict__ thb2,
        const float* __restrict__ lhW1, const float* __restrict__ lhb1,
        const float* __restrict__ lhW2, const float* __restrict__ lhb2,
        const float* __restrict__ shW1, const float* __restrict__ shb1,
        const float* __restrict__ shW2, const float* __restrict__ shb2,
        float* __restrict__ out, int B) {
    int g = blockIdx.x, t = threadIdx.x;
    __shared__ float ge[HH];
    __shared__ float hT[32], hL[32], hS[16];
    int lo = lower_bound_i(batch, N, g);
    int hi = lower_bound_i(batch, N, g + 1);
    float cnt = (float)(hi - lo);
    ge[t] = gsum[g * HH + t] / fmaxf(cnt, 1.0f);
    __syncthreads();
    if (t < 32) {
        float a = thb1[t];
        for (int k = 0; k < HH; ++k) a += ge[k] * thW1[k * 32 + t];
        hT[t] = fmaxf(a, 0.f);
    } else {
        int j = t - 32;
        float a = lhb1[j];
        for (int k = 0; k < HH; ++k) a += ge[k] * lhW1[k * 32 + j];
        hL[j] = fmaxf(a, 0.f);
    }
    __syncthreads();
    if (t < 16) {
        float a = shb1[t];
        for (int k = 0; k < HH; ++k) a += ge[k] * shW1[k * 16 + t];
        hS[t] = fmaxf(a, 0.f);
    }
    __syncthreads();
    if (t < 6) {
        float a = thb2[t];
        for (int j = 0; j < 32; ++j) a += hT[j] * thW2[j * 6 + t];
        out[g * 6 + t] = a;
    } else if (t >= 8 && t < 10) {
        int o = t - 8;
        float a = lhb2[o];
        for (int j = 0; j < 32; ++j) a += hL[j] * lhW2[j * 2 + o];
        out[B * 6 + g * 2 + o] = 1.f / (1.f + expf(-a));
    } else if (t == 12) {
        float a = shb2[0];
        for (int j = 0; j < 16; ++j) a += hS[j] * shW2[j];
        out[B * 8 + g] = 1.f / (1.f + expf(-a));
    }
}

// ---------------------------------------------------------------- launch
extern "C" void kernel_launch(void* const* d_in, const int* in_sizes, int n_in,
                              void* d_out, int out_size, void* d_ws, size_t ws_size,
                              hipStream_t stream) {
    const float* x   = (const float*)d_in[0];
    const int*   ei  = (const int*)d_in[1];
    const int*   bat = (const int*)d_in[2];
    const float* W1 = (const float*)d_in[3];  const float* b1 = (const float*)d_in[4];
    const float* W2 = (const float*)d_in[5];  const float* b2 = (const float*)d_in[6];
    const float* W3 = (const float*)d_in[7];  const float* b3 = (const float*)d_in[8];
    const float* bn1g = (const float*)d_in[9];  const float* bn1b = (const float*)d_in[10];
    const float* bn1m = (const float*)d_in[11]; const float* bn1v = (const float*)d_in[12];
    const float* bn2g = (const float*)d_in[13]; const float* bn2b = (const float*)d_in[14];
    const float* bn2m = (const float*)d_in[15]; const float* bn2v = (const float*)d_in[16];
    const float* bn3g = (const float*)d_in[17]; const float* bn3b = (const float*)d_in[18];
    const float* bn3m = (const float*)d_in[19]; const float* bn3v = (const float*)d_in[20];
    const float* thW1 = (const float*)d_in[21]; const float* thb1 = (const float*)d_in[22];
    const float* thW2 = (const float*)d_in[23]; const float* thb2 = (const float*)d_in[24];
    const float* lhW1 = (const float*)d_in[25]; const float* lhb1 = (const float*)d_in[26];
    const float* lhW2 = (const float*)d_in[27]; const float* lhb2 = (const float*)d_in[28];
    const float* shW1 = (const float*)d_in[29]; const float* shb1 = (const float*)d_in[30];
    const float* shW2 = (const float*)d_in[31]; const float* shb2 = (const float*)d_in[32];
    float* out = (float*)d_out;

    const int N = in_sizes[0] / 3;
    const int E = in_sizes[1] / 2;
    const int B = out_size / 9;          // 6 + 2 + 1 per graph
    const int NB = (N + 255) >> 8;       // buckets of 256 nodes
    const int* esrc = ei;
    const int* edst = ei + E;

    // workspace layout (256B aligned)
    char* w = (char*)d_ws;
    size_t off = 0;
    auto alloc = [&](size_t bytes) -> void* {
        void* p = w + off;
        off += (bytes + 255) & ~(size_t)255;
        return p;
    };
    int*   rowstart   = (int*)  alloc((size_t)(N + 1) * 4);
    float* dis        = (float*)alloc((size_t)N * 4);
    int*   csr        = (int*)  alloc((size_t)E * 4);
    int*   blockhist  = (int*)  alloc((size_t)NBLK_SCAT * 256 * 4);
    int*   bucketbase = (int*)  alloc((size_t)(NB + 1) * 4);
    float* hbuf       = (float*)alloc((size_t)N * HH * 4);
    unsigned short* mtbuf = (unsigned short*)alloc((size_t)N * HH * 2);
    float* gsum       = (float*)alloc((size_t)B * HH * 4);
    int*   bucketbuf  = (int*)mtbuf;     // reuse: free until mt1_kernel (E*4 <= N*HH*2)
    (void)ws_size;

    const int TB = 256;
    const int echunk = (E + NBLK_SCAT - 1) / NBLK_SCAT;
    // CSR build: hist -> bucketscan -> offsets -> scatter -> per-bucket deg/scan/permute
    init_kernel<<<(B * HH + TB - 1) / TB, TB, 0, stream>>>(gsum, B * HH);
    hist_kernel<<<NBLK_SCAT, TB, 0, stream>>>(edst, blockhist, E, echunk);
    bucketscan_kernel<<<1, TB, 0, stream>>>(blockhist, bucketbase, NB, E);
    offsets_kernel<<<NB, 64, 0, stream>>>(bucketbase, blockhist, NB);
    scatterA_kernel<<<NBLK_SCAT, TB, 0, stream>>>(esrc, edst, blockhist, bucketbuf, E, echunk);
    bucket_to_csr_kernel<<<NB, TB, 0, stream>>>(bucketbuf, bucketbase, rowstart, dis, csr, N, E);

    int gatherBlocks = (N + 3) / 4;
    int gemmBlocks = (N + 63) / 64;
    // layer 1
    mt1_kernel<<<(N * HH + TB - 1) / TB, TB, 0, stream>>>(x, W1, dis, mtbuf, N);
    gather_bn_kernel<<<gatherBlocks, TB, 0, stream>>>(mtbuf, rowstart, csr, dis,
            b1, bn1g, bn1b, bn1m, bn1v, hbuf, N);
    // layer 2
    gemm_scale_kernel<<<gemmBlocks, TB, 0, stream>>>(hbuf, W2, dis, mtbuf, N);
    gather_bn_kernel<<<gatherBlocks, TB, 0, stream>>>(mtbuf, rowstart, csr, dis,
            b2, bn2g, bn2b, bn2m, bn2v, hbuf, N);
    // layer 3
    gemm_scale_kernel<<<gemmBlocks, TB, 0, stream>>>(hbuf, W3, dis, mtbuf, N);
    gather_bn_kernel<<<gatherBlocks, TB, 0, stream>>>(mtbuf, rowstart, csr, dis,
            b3, bn3g, bn3b, bn3m, bn3v, hbuf, N);

    // pool (gsum zeroed in init_kernel) + heads
    const int PW_BLOCKS = 512;
    int chunk = (N + PW_BLOCKS * 4 - 1) / (PW_BLOCKS * 4);
    pool_partial_kernel<<<PW_BLOCKS, TB, 0, stream>>>(hbuf, bat, gsum, N, chunk);

    heads_kernel<<<B, 64, 0, stream>>>(gsum, bat, N, thW1, thb1, thW2, thb2,
            lhW1, lhb1, lhW2, lhb2, shW1, shb1, shW2, shb2, out, B);
}

// Round 15
// 216.898 us; speedup vs baseline: 1.5400x; 1.5400x over previous
//
#include <hip/hip_runtime.h>
#include <hip/hip_bf16.h>
#include <math.h>

#define HH 64            // hidden channels
#define EPS 1e-5f
#define STAGE_CAP 12288  // per-bucket LDS staging capacity (3x avg bucket size)
#define NBLK_SCAT 192    // partition blocks (must match between hist and scatter)
#define PER_LANE 3       // ceil(NBLK_SCAT / 64)

// ---------------------------------------------------------------- utilities
__device__ __forceinline__ int lower_bound_i(const int* a, int n, int key) {
    int lo = 0, hi = n;
    while (lo < hi) { int mid = (lo + hi) >> 1; if (a[mid] < key) lo = mid + 1; else hi = mid; }
    return lo;
}

__device__ __forceinline__ unsigned short f2bf(float f) {
    unsigned int u = __float_as_uint(f);
    unsigned int r = (u + 0x7FFFu + ((u >> 16) & 1u)) >> 16;   // RNE
    return (unsigned short)r;
}
__device__ __forceinline__ float bf2f(unsigned short b) {
    return __uint_as_float(((unsigned int)b) << 16);
}
__device__ __forceinline__ float bflo(unsigned int u) { return __uint_as_float(u << 16); }
__device__ __forceinline__ float bfhi(unsigned int u) { return __uint_as_float(u & 0xFFFF0000u); }

// ---------------------------------------------------------------- init (gsum only)
__global__ void init_kernel(float* gsum, int NG) {
    int t = blockIdx.x * blockDim.x + threadIdx.x;
    if (t < NG) gsum[t] = 0.f;
}

// pass A1: per-block histogram over buckets (LDS only, no global atomics)
__global__ __launch_bounds__(256) void hist_kernel(const int* __restrict__ dst,
        int* __restrict__ blockhist, int E, int chunk) {
    __shared__ int hist[256];
    int tid = threadIdx.x, blk = blockIdx.x;
    hist[tid] = 0;
    __syncthreads();
    int s = blk * chunk, e = s + chunk; if (e > E) e = E;
    for (int i = s + tid; i < e; i += 256) atomicAdd(&hist[dst[i] >> 8], 1);
    __syncthreads();
    blockhist[blk * 256 + tid] = hist[tid];
}

// pass A1b: single block; column-sum blockhist -> bucket totals -> exclusive scan
__global__ __launch_bounds__(256) void bucketscan_kernel(const int* __restrict__ blockhist,
        int* __restrict__ bucketbase, int NB, int E) {
    __shared__ int wsum2[4];
    int tid = threadIdx.x, lane = tid & 63, wid = tid >> 6;
    int s = 0;
    if (tid < NB) {
        for (int i = 0; i < NBLK_SCAT; ++i) s += blockhist[i * 256 + tid];
    }
    int incl = s;
    #pragma unroll
    for (int off = 1; off < 64; off <<= 1) {
        int n = __shfl_up(incl, off);
        if (lane >= off) incl += n;
    }
    if (lane == 63) wsum2[wid] = incl;
    __syncthreads();
    int wbase = 0;
    #pragma unroll
    for (int k = 0; k < 4; ++k) if (k < wid) wbase += wsum2[k];
    if (tid < NB) bucketbase[tid] = wbase + incl - s;
    if (tid == 0) bucketbase[NB] = E;
}

// pass A2: per-bucket column scan of blockhist -> per-block write cursors
__global__ __launch_bounds__(64) void offsets_kernel(const int* __restrict__ bucketbase,
        int* __restrict__ blockhist, int NB) {
    int b = blockIdx.x;
    int lane = threadIdx.x;
    int v[PER_LANE];
    int base = lane * PER_LANE;
    int s = 0;
    #pragma unroll
    for (int k = 0; k < PER_LANE; ++k) {
        int i = base + k;
        v[k] = (i < NBLK_SCAT) ? blockhist[i * 256 + b] : 0;
        s += v[k];
    }
    int incl = s;
    #pragma unroll
    for (int off = 1; off < 64; off <<= 1) {
        int n = __shfl_up(incl, off);
        if (lane >= off) incl += n;
    }
    int excl = incl - s + bucketbase[b];
    #pragma unroll
    for (int k = 0; k < PER_LANE; ++k) {
        int i = base + k;
        if (i < NBLK_SCAT) { blockhist[i * 256 + b] = excl; excl += v[k]; }
    }
}

// pass A3: scatter edges to bucket regions using LDS cursors
__global__ __launch_bounds__(256) void scatterA_kernel(const int* __restrict__ src,
        const int* __restrict__ dst, const int* __restrict__ blockhist,
        int* __restrict__ buf, int E, int chunk) {
    __shared__ int lcur[256];
    int tid = threadIdx.x, blk = blockIdx.x;
    lcur[tid] = blockhist[blk * 256 + tid];
    __syncthreads();
    int s = blk * chunk, e = s + chunk; if (e > E) e = E;
    for (int i = s + tid; i < e; i += 256) {
        int d = dst[i];
        int b = d >> 8;
        int p = atomicAdd(&lcur[b], 1);
        buf[p] = ((d & 255) << 24) | src[i];    // pack local-dst | src (src < 2^24)
    }
}

// pass B: per bucket: local degree hist + scan (writes rowstart, dis), permute to csr
__global__ __launch_bounds__(256) void bucket_to_csr_kernel(const int* __restrict__ buf,
        const int* __restrict__ bucketbase, int* __restrict__ rowstart,
        float* __restrict__ dis, int* __restrict__ csr, int N, int E) {
    __shared__ int ldeg[256];
    __shared__ int cur[256];
    __shared__ int wsum2[4];
    __shared__ int stage[STAGE_CAP];
    int b = blockIdx.x;
    int nodeStart = b << 8;
    int nodeEnd = nodeStart + 256; if (nodeEnd > N) nodeEnd = N;
    int nloc = nodeEnd - nodeStart;
    int base = bucketbase[b];
    int nE = bucketbase[b + 1] - base;
    int tid = threadIdx.x;
    int lane = tid & 63, wid = tid >> 6;
    ldeg[tid] = 0;
    __syncthreads();
    for (int i = tid; i < nE; i += 256)
        atomicAdd(&ldeg[((unsigned)buf[base + i]) >> 24], 1);
    __syncthreads();
    int d = ldeg[tid];
    int incl = d;
    #pragma unroll
    for (int off = 1; off < 64; off <<= 1) {
        int n = __shfl_up(incl, off);
        if (lane >= off) incl += n;
    }
    if (lane == 63) wsum2[wid] = incl;
    __syncthreads();
    int wbase = 0;
    #pragma unroll
    for (int k = 0; k < 4; ++k) if (k < wid) wbase += wsum2[k];
    int excl = wbase + incl - d;
    cur[tid] = excl;
    if (tid < nloc) {
        rowstart[nodeStart + tid] = base + excl;
        dis[nodeStart + tid] = rsqrtf((float)d + 1.0f);
    }
    if (b == 0 && tid == 0) rowstart[N] = E;
    __syncthreads();
    if (nE <= STAGE_CAP) {
        for (int i = tid; i < nE; i += 256) {
            int u = buf[base + i];
            int l = ((unsigned)u) >> 24;
            int p = atomicAdd(&cur[l], 1);
            stage[p] = u & 0xFFFFFF;
        }
        __syncthreads();
        for (int i = tid; i < nE; i += 256) csr[base + i] = stage[i];
    } else {
        for (int i = tid; i < nE; i += 256) {
            int u = buf[base + i];
            int l = ((unsigned)u) >> 24;
            int p = atomicAdd(&cur[l], 1);
            csr[base + p] = u & 0xFFFFFF;
        }
    }
}

// ---------------------------------------------------------------- layer 1 GEMM (IN=3) -> bf16 mt
__global__ void mt1_kernel(const float* __restrict__ x, const float* __restrict__ W1,
                           const float* __restrict__ dis, unsigned short* __restrict__ mt, int N) {
    int t = blockIdx.x * blockDim.x + threadIdx.x;
    if (t < N * HH) {
        int v = t >> 6, c = t & 63;
        float m = x[v * 3 + 0] * W1[0 * HH + c]
                + x[v * 3 + 1] * W1[1 * HH + c]
                + x[v * 3 + 2] * W1[2 * HH + c];
        mt[t] = f2bf(m * dis[v]);
    }
}

// ---------------------------------------------------------------- 64x64 GEMM + row scale -> bf16 mt
__global__ __launch_bounds__(256) void gemm_scale_kernel(const float* __restrict__ h,
        const float* __restrict__ W, const float* __restrict__ dis,
        unsigned short* __restrict__ mt, int N) {
    __shared__ unsigned int wsp[HH * 34];
    __shared__ unsigned int hs2[64 * 34];
    int tid = threadIdx.x;
    int lane = tid & 63, wid = tid >> 6;
    {
        int c = tid & 63;
        for (int k2 = tid >> 6; k2 < 32; k2 += 4) {
            float a = W[(2 * k2) * HH + c];
            float b = W[(2 * k2 + 1) * HH + c];
            wsp[c * 34 + k2] = (unsigned)f2bf(a) | ((unsigned)f2bf(b) << 16);
        }
    }
    int v0 = blockIdx.x * 64;
    int nv = N - v0; if (nv > 64) nv = 64;
    for (int idx = tid; idx < 64 * 32; idx += 256) {
        int n = idx >> 5, k2 = idx & 31;
        int vsrc = v0 + ((n < nv) ? n : 0);
        float a = h[(size_t)vsrc * HH + 2 * k2];
        float b = h[(size_t)vsrc * HH + 2 * k2 + 1];
        hs2[n * 34 + k2] = (unsigned)f2bf(a) | ((unsigned)f2bf(b) << 16);
    }
    __syncthreads();
    for (int n = wid * 16; n < wid * 16 + 16; ++n) {
        int vg = v0 + n;
        if (n >= nv) break;
        float acc = 0.f;
        #pragma unroll 4
        for (int k2g = 0; k2g < 16; ++k2g) {
            uint2 wv = *(const uint2*)&wsp[lane * 34 + 2 * k2g];
            uint2 hv = *(const uint2*)&hs2[n * 34 + 2 * k2g];
            acc = fmaf(bflo(hv.x), bflo(wv.x), acc);
            acc = fmaf(bfhi(hv.x), bfhi(wv.x), acc);
            acc = fmaf(bflo(hv.y), bflo(wv.y), acc);
            acc = fmaf(bfhi(hv.y), bfhi(wv.y), acc);
        }
        mt[(size_t)vg * HH + lane] = f2bf(acc * dis[vg]);
    }
}

// ---------------------------------------------------------------- gather + bias + BN + ReLU
__global__ __launch_bounds__(256) void gather_bn_kernel(const unsigned short* __restrict__ mt,
        const int* __restrict__ rowstart, const int* __restrict__ csr_src,
        const float* __restrict__ dis, const float* __restrict__ bias,
        const float* __restrict__ gam, const float* __restrict__ beta,
        const float* __restrict__ mu, const float* __restrict__ var,
        float* __restrict__ hout, int N) {
    int lane = threadIdx.x & 63, wid = threadIdx.x >> 6;
    int v = blockIdx.x * 4 + wid;
    if (v >= N) return;
    int start = rowstart[v], end = rowstart[v + 1];
    float acc = bf2f(mt[v * HH + lane]);   // self-loop term (m[v]*dis[v])
    for (int base = start; base < end; base += 64) {
        int idx = (base + lane < end) ? csr_src[base + lane] : 0;
        int cnt = end - base; if (cnt > 64) cnt = 64;
        int j = 0;
        for (; j + 15 < cnt; j += 16) {
            int s0 = __shfl(idx, j),      s1 = __shfl(idx, j + 1);
            int s2 = __shfl(idx, j + 2),  s3 = __shfl(idx, j + 3);
            int s4 = __shfl(idx, j + 4),  s5 = __shfl(idx, j + 5);
            int s6 = __shfl(idx, j + 6),  s7 = __shfl(idx, j + 7);
            int s8 = __shfl(idx, j + 8),  s9 = __shfl(idx, j + 9);
            int sa = __shfl(idx, j + 10), sb = __shfl(idx, j + 11);
            int sc = __shfl(idx, j + 12), sd = __shfl(idx, j + 13);
            int se = __shfl(idx, j + 14), sf = __shfl(idx, j + 15);
            float v0 = bf2f(mt[s0 * HH + lane]);
            float v1 = bf2f(mt[s1 * HH + lane]);
            float v2 = bf2f(mt[s2 * HH + lane]);
            float v3 = bf2f(mt[s3 * HH + lane]);
            float v4 = bf2f(mt[s4 * HH + lane]);
            float v5 = bf2f(mt[s5 * HH + lane]);
            float v6 = bf2f(mt[s6 * HH + lane]);
            float v7 = bf2f(mt[s7 * HH + lane]);
            float v8 = bf2f(mt[s8 * HH + lane]);
            float v9 = bf2f(mt[s9 * HH + lane]);
            float va = bf2f(mt[sa * HH + lane]);
            float vb = bf2f(mt[sb * HH + lane]);
            float vc = bf2f(mt[sc * HH + lane]);
            float vd = bf2f(mt[sd * HH + lane]);
            float ve = bf2f(mt[se * HH + lane]);
            float vf = bf2f(mt[sf * HH + lane]);
            acc += v0; acc += v1; acc += v2; acc += v3;
            acc += v4; acc += v5; acc += v6; acc += v7;
            acc += v8; acc += v9; acc += va; acc += vb;
            acc += vc; acc += vd; acc += ve; acc += vf;
        }
        for (; j + 7 < cnt; j += 8) {
            int s0 = __shfl(idx, j),     s1 = __shfl(idx, j + 1);
            int s2 = __shfl(idx, j + 2), s3 = __shfl(idx, j + 3);
            int s4 = __shfl(idx, j + 4), s5 = __shfl(idx, j + 5);
            int s6 = __shfl(idx, j + 6), s7 = __shfl(idx, j + 7);
            float v0 = bf2f(mt[s0 * HH + lane]);
            float v1 = bf2f(mt[s1 * HH + lane]);
            float v2 = bf2f(mt[s2 * HH + lane]);
            float v3 = bf2f(mt[s3 * HH + lane]);
            float v4 = bf2f(mt[s4 * HH + lane]);
            float v5 = bf2f(mt[s5 * HH + lane]);
            float v6 = bf2f(mt[s6 * HH + lane]);
            float v7 = bf2f(mt[s7 * HH + lane]);
            acc += v0; acc += v1; acc += v2; acc += v3;
            acc += v4; acc += v5; acc += v6; acc += v7;
        }
        for (; j < cnt; ++j) acc += bf2f(mt[__shfl(idx, j) * HH + lane]);
    }
    float val = acc * dis[v] + bias[lane];
    val = (val - mu[lane]) * rsqrtf(var[lane] + EPS) * gam[lane] + beta[lane];
    hout[v * HH + lane] = fmaxf(val, 0.f);
}

// ---------------------------------------------------------------- pool partial sums
__global__ __launch_bounds__(256) void pool_partial_kernel(const float* __restrict__ h,
        const int* __restrict__ batch, float* __restrict__ gsum, int N, int chunk) {
    int lane = threadIdx.x & 63, wid = threadIdx.x >> 6;
    int w = blockIdx.x * 4 + wid;
    int start = w * chunk;
    int end = start + chunk; if (end > N) end = N;
    if (start >= end) return;
    int g = batch[start];
    float acc = 0.f;
    for (int i = start; i < end; ++i) {
        int gi = batch[i];
        if (gi != g) {
            atomicAdd(&gsum[g * HH + lane], acc);
            acc = 0.f; g = gi;
        }
        acc += h[i * HH + lane];
    }
    atomicAdd(&gsum[g * HH + lane], acc);
}

// ---------------------------------------------------------------- MLP heads (+ mean divide)
__global__ __launch_bounds__(64) void heads_kernel(const float* __restrict__ gsum,
        const int* __restrict__ batch, int N,
        const float* __restrict__ thW1, const float* __restrict__ thb1,
        const float* __restrict__ thW2, const float* __restrict__ thb2,
        const float* __restrict__ lhW1, const float* __restrict__ lhb1,
        const float* __restrict__ lhW2, const float* __restrict__ lhb2,
        const float* __restrict__ shW1, const float* __restrict__ shb1,
        const float* __restrict__ shW2, const float* __restrict__ shb2,
        float* __restrict__ out, int B) {
    int g = blockIdx.x, t = threadIdx.x;
    __shared__ float ge[HH];
    __shared__ float hT[32], hL[32], hS[16];
    int lo = lower_bound_i(batch, N, g);
    int hi = lower_bound_i(batch, N, g + 1);
    float cnt = (float)(hi - lo);
    ge[t] = gsum[g * HH + t] / fmaxf(cnt, 1.0f);
    __syncthreads();
    if (t < 32) {
        float a = thb1[t];
        for (int k = 0; k < HH; ++k) a += ge[k] * thW1[k * 32 + t];
        hT[t] = fmaxf(a, 0.f);
    } else {
        int j = t - 32;
        float a = lhb1[j];
        for (int k = 0; k < HH; ++k) a += ge[k] * lhW1[k * 32 + j];
        hL[j] = fmaxf(a, 0.f);
    }
    __syncthreads();
    if (t < 16) {
        float a = shb1[t];
        for (int k = 0; k < HH; ++k) a += ge[k] * shW1[k * 16 + t];
        hS[t] = fmaxf(a, 0.f);
    }
    __syncthreads();
    if (t < 6) {
        float a = thb2[t];
        for (int j = 0; j < 32; ++j) a += hT[j] * thW2[j * 6 + t];
        out[g * 6 + t] = a;
    } else if (t >= 8 && t < 10) {
        int o = t - 8;
        float a = lhb2[o];
        for (int j = 0; j < 32; ++j) a += hL[j] * lhW2[j * 2 + o];
        out[B * 6 + g * 2 + o] = 1.f / (1.f + expf(-a));
    } else if (t == 12) {
        float a = shb2[0];
        for (int j = 0; j < 16; ++j) a += hS[j] * shW2[j];
        out[B * 8 + g] = 1.f / (1.f + expf(-a));
    }
}

// ---------------------------------------------------------------- launch
extern "C" void kernel_launch(void* const* d_in, const int* in_sizes, int n_in,
                              void* d_out, int out_size, void* d_ws, size_t ws_size,
                              hipStream_t stream) {
    const float* x   = (const float*)d_in[0];
    const int*   ei  = (const int*)d_in[1];
    const int*   bat = (const int*)d_in[2];
    const float* W1 = (const float*)d_in[3];  const float* b1 = (const float*)d_in[4];
    const float* W2 = (const float*)d_in[5];  const float* b2 = (const float*)d_in[6];
    const float* W3 = (const float*)d_in[7];  const float* b3 = (const float*)d_in[8];
    const float* bn1g = (const float*)d_in[9];  const float* bn1b = (const float*)d_in[10];
    const float* bn1m = (const float*)d_in[11]; const float* bn1v = (const float*)d_in[12];
    const float* bn2g = (const float*)d_in[13]; const float* bn2b = (const float*)d_in[14];
    const float* bn2m = (const float*)d_in[15]; const float* bn2v = (const float*)d_in[16];
    const float* bn3g = (const float*)d_in[17]; const float* bn3b = (const float*)d_in[18];
    const float* bn3m = (const float*)d_in[19]; const float* bn3v = (const float*)d_in[20];
    const float* thW1 = (const float*)d_in[21]; const float* thb1 = (const float*)d_in[22];
    const float* thW2 = (const float*)d_in[23]; const float* thb2 = (const float*)d_in[24];
    const float* lhW1 = (const float*)d_in[25]; const float* lhb1 = (const float*)d_in[26];
    const float* lhW2 = (const float*)d_in[27]; const float* lhb2 = (const float*)d_in[28];
    const float* shW1 = (const float*)d_in[29]; const float* shb1 = (const float*)d_in[30];
    const float* shW2 = (const float*)d_in[31]; const float* shb2 = (const float*)d_in[32];
    float* out = (float*)d_out;

    const int N = in_sizes[0] / 3;
    const int E = in_sizes[1] / 2;
    const int B = out_size / 9;          // 6 + 2 + 1 per graph
    const int NB = (N + 255) >> 8;       // buckets of 256 nodes
    const int* esrc = ei;
    const int* edst = ei + E;

    // workspace layout (256B aligned)
    char* w = (char*)d_ws;
    size_t off = 0;
    auto alloc = [&](size_t bytes) -> void* {
        void* p = w + off;
        off += (bytes + 255) & ~(size_t)255;
        return p;
    };
    int*   rowstart   = (int*)  alloc((size_t)(N + 1) * 4);
    float* dis        = (float*)alloc((size_t)N * 4);
    int*   csr        = (int*)  alloc((size_t)E * 4);
    int*   blockhist  = (int*)  alloc((size_t)NBLK_SCAT * 256 * 4);
    int*   bucketbase = (int*)  alloc((size_t)(NB + 1) * 4);
    float* hbuf       = (float*)alloc((size_t)N * HH * 4);
    unsigned short* mtbuf = (unsigned short*)alloc((size_t)N * HH * 2);
    float* gsum       = (float*)alloc((size_t)B * HH * 4);
    int*   bucketbuf  = (int*)mtbuf;     // reuse: free until mt1_kernel (E*4 <= N*HH*2)
    (void)ws_size;

    const int TB = 256;
    const int echunk = (E + NBLK_SCAT - 1) / NBLK_SCAT;
    // CSR build: hist -> bucketscan -> offsets -> scatter -> per-bucket deg/scan/permute
    init_kernel<<<(B * HH + TB - 1) / TB, TB, 0, stream>>>(gsum, B * HH);
    hist_kernel<<<NBLK_SCAT, TB, 0, stream>>>(edst, blockhist, E, echunk);
    bucketscan_kernel<<<1, TB, 0, stream>>>(blockhist, bucketbase, NB, E);
    offsets_kernel<<<NB, 64, 0, stream>>>(bucketbase, blockhist, NB);
    scatterA_kernel<<<NBLK_SCAT, TB, 0, stream>>>(esrc, edst, blockhist, bucketbuf, E, echunk);
    bucket_to_csr_kernel<<<NB, TB, 0, stream>>>(bucketbuf, bucketbase, rowstart, dis, csr, N, E);

    int gatherBlocks = (N + 3) / 4;
    int gemmBlocks = (N + 63) / 64;
    // layer 1
    mt1_kernel<<<(N * HH + TB - 1) / TB, TB, 0, stream>>>(x, W1, dis, mtbuf, N);
    gather_bn_kernel<<<gatherBlocks, TB, 0, stream>>>(mtbuf, rowstart, csr, dis,
            b1, bn1g, bn1b, bn1m, bn1v, hbuf, N);
    // layer 2
    gemm_scale_kernel<<<gemmBlocks, TB, 0, stream>>>(hbuf, W2, dis, mtbuf, N);
    gather_bn_kernel<<<gatherBlocks, TB, 0, stream>>>(mtbuf, rowstart, csr, dis,
            b2, bn2g, bn2b, bn2m, bn2v, hbuf, N);
    // layer 3
    gemm_scale_kernel<<<gemmBlocks, TB, 0, stream>>>(hbuf, W3, dis, mtbuf, N);
    gather_bn_kernel<<<gatherBlocks, TB, 0, stream>>>(mtbuf, rowstart, csr, dis,
            b3, bn3g, bn3b, bn3m, bn3v, hbuf, N);

    // pool (gsum zeroed in init_kernel) + heads
    const int PW_BLOCKS = 512;
    int chunk = (N + PW_BLOCKS * 4 - 1) / (PW_BLOCKS * 4);
    pool_partial_kernel<<<PW_BLOCKS, TB, 0, stream>>>(hbuf, bat, gsum, N, chunk);

    heads_kernel<<<B, 64, 0, stream>>>(gsum, bat, N, thW1, thb1, thW2, thb2,
            lhW1, lhb1, lhW2, lhb2, shW1, shb1, shW2, shb2, out, B);
}